// Round 13
// baseline (180.532 us; speedup 1.0000x reference)
//
#include <hip/hip_runtime.h>
#include <hip/hip_bf16.h>
#include <math.h>

#define B_ 64
#define I_ 2048
#define K_ 16
#define N_ 32
#define D_ 32
#define SCH_ 16     // i-chunks for mfma sweep (128 i each)

#define AS1 __attribute__((address_space(1)))
#define AS3 __attribute__((address_space(3)))

typedef __attribute__((ext_vector_type(8))) short short8_t;   // 8 bf16
typedef __attribute__((ext_vector_type(4))) float f32x4_t;

// ws offsets (floats)
#define OFF_INT   0u           // inT   [I][K][B]        2097152
#define OFF_CT    2097152u     // cT    [N][I][B]        4194304
#define OFF_BT    6291456u     // bT    [N][I][B]        4194304
#define OFF_SPART 10485760u    // spart [N][SCH][B][D]   1048576
#define OFF_OFRAG 11534336u    // ofrag [N][4][64] uint4 =  32768 f-slots
#define OFF_XFRAG 11599872u    // xfrag [4][1024][64] uint4 = 1048576 f-slots
#define OFF_WFS   12648448u    // wfs [N][1024][2][64] uint4 = 16777216 (64 MiB)
#define OFF_WFU   29425664u    // wfu [N][I][64] uint4       = 16777216 (64 MiB)
// total 176.25 MiB (ws = 512 MiB per harness poison fills)

__device__ __forceinline__ unsigned int pk_bf16(float lo, float hi) {
    union { __hip_bfloat162 h2; unsigned int u; } cv;
    cv.h2 = __float22bfloat162_rn(float2{lo, hi});
    return cv.u;
}

// ---------------- fused: transpose inputs -> inT  +  pack xfrag ----------------
__global__ __launch_bounds__(256) void k_prep(const float* __restrict__ in,
                                              float* __restrict__ inT,
                                              uint4* __restrict__ xfrag) {
    __shared__ float lds[B_][K_ + 1];
    const int i = blockIdx.x;
    const int t = threadIdx.x;
    const int b = t >> 2, kq = t & 3;
    const float4 v = *(const float4*)(in + ((size_t)b * I_ + i) * K_ + kq * 4);
    lds[b][kq * 4 + 0] = v.x; lds[b][kq * 4 + 1] = v.y;
    lds[b][kq * 4 + 2] = v.z; lds[b][kq * 4 + 3] = v.w;
    __syncthreads();
#pragma unroll
    for (int q = 0; q < 4; ++q) {
        const int j = t + q * 256;          // j = k*64 + b
        const int k = j >> 6, bb = j & 63;
        inT[(size_t)i * (K_ * B_) + j] = lds[bb][k];
    }
    // xfrag entries for this i: 128 threads, one uint4 each
    if (t < 128) {
        const int m = t >> 5, r = t & 31, gl = r >> 4, kl = r & 15;
        const int bb = m * 16 + kl, k0 = 8 * gl;
        union { unsigned int u[4]; uint4 q; } o;
#pragma unroll
        for (int p = 0; p < 4; ++p)
            o.u[p] = pk_bf16(lds[bb][k0 + 2 * p], lds[bb][k0 + 2 * p + 1]);
        xfrag[((size_t)m * 1024 + (i >> 1)) * 64 + (2 * (i & 1) + gl) * 16 + kl] = o.q;
    }
}

// ---------------- pre-pack W -> bf16 fragments (throughput rewrite) ----------------
// 512 thr, 16 i per block. Per sub-chunk (4 i = 2048 f): async stage -> LDS,
// waves 0-3 emit wfu frags, waves 4-7 emit wfs frags. Layouts identical to r11.
__global__ __launch_bounds__(512, 4) void k_wpack(const float* __restrict__ W,
                                                  uint4* __restrict__ wfs,
                                                  uint4* __restrict__ wfu) {
    __shared__ __align__(16) float lds[2048];
    const int ib = blockIdx.x * 16;    // 16 i per block
    const int n = blockIdx.y;
    const int t = threadIdx.x, w = t >> 6, lane = t & 63;
    const float* wg = W + ((size_t)n * I_ + ib) * 512;

    for (int sc = 0; sc < 4; ++sc) {
        __syncthreads();                   // prior compute done before overwrite
        {
            const float4* s4 = (const float4*)(wg + sc * 2048);
            float4* d4 = (float4*)lds;
            __builtin_amdgcn_global_load_lds(
                (const AS1 void*)(const void*)(s4 + w * 64 + lane),
                (AS3 void*)(void*)(d4 + w * 64), 16, 0, 0);
        }
        __syncthreads();                   // drains vmcnt -> tile resident

        if (t < 256) {
            // wfu A-frag: il = i_local, pairs W[i][8g+2p(+1)][kl]
            const int il = t >> 6, l = t & 63, g = l >> 4, kl = l & 15;
            const float* base = lds + il * 512;
            union { unsigned int u[4]; uint4 q; } o;
#pragma unroll
            for (int p = 0; p < 4; ++p)
                o.u[p] = pk_bf16(base[(8 * g + 2 * p) * 16 + kl],
                                 base[(8 * g + 2 * p + 1) * 16 + kl]);
            wfu[((size_t)n * I_ + ib + sc * 4 + il) * 64 + l] = o.q;
        } else {
            // wfs B-frag: kkl selects i-pair, nt selects d-half
            const int u2 = t - 256;
            const int kkl = u2 >> 7, r = u2 & 127, nt = r >> 6, l = r & 63, g = l >> 4;
            const float* p = lds + kkl * 1024 + (g >> 1) * 512 + nt * 256
                             + (l & 15) * 16 + (g & 1) * 8;
            const float4 f0 = *(const float4*)p;
            const float4 f1 = *(const float4*)(p + 4);
            union { unsigned int u[4]; uint4 q; } o;
            o.u[0] = pk_bf16(f0.x, f0.y); o.u[1] = pk_bf16(f0.z, f0.w);
            o.u[2] = pk_bf16(f1.x, f1.y); o.u[3] = pk_bf16(f1.z, f1.w);
            const int kk = (ib >> 1) + sc * 2 + kkl;
            wfs[(((size_t)n * 1024 + kk) * 2 + nt) * 64 + l] = o.q;
        }
    }
}

// ---------------- MFMA s-sweep (verified r11) ----------------
template<int UNIFORM>
__global__ __launch_bounds__(512, 2) void k_sweep_mfma(const uint4* __restrict__ wfs,
                                                       const uint4* __restrict__ xfrag,
                                                       const float* __restrict__ cT,
                                                       float* __restrict__ spart) {
    __shared__ float red[2][B_][D_ + 1];
    const int n = blockIdx.y, ch = blockIdx.x;
    const int t = threadIdx.x, w = t >> 6, l = t & 63;
    const int m = w >> 1, ks = w & 1;

    f32x4_t acc0 = {0.f, 0.f, 0.f, 0.f};
    f32x4_t acc1 = {0.f, 0.f, 0.f, 0.f};

    const uint4* xf = xfrag + (size_t)m * 65536 + l;            // + kk*64
    const uint4* wf = wfs + (size_t)n * (1024 * 128) + l;       // + kk*128 (+64 nt=1)
    const int kk0 = ch * 64 + ks * 32;

    for (int tt = 0; tt < 32; ++tt) {
        const int kk = kk0 + tt;
        union { uint4 q; unsigned int u[4]; } xv;
        xv.q = xf[(size_t)kk * 64];
        union { unsigned int u[4]; short8_t v; } af;
        if (UNIFORM) {
            af.u[0] = xv.u[0]; af.u[1] = xv.u[1];
            af.u[2] = xv.u[2]; af.u[3] = xv.u[3];
        } else {
            const float c = cT[((size_t)n * I_ + 2 * kk + (l >> 5)) * B_
                               + m * 16 + (l & 15)];
#pragma unroll
            for (int p = 0; p < 4; ++p) {
                const unsigned int uu = xv.u[p];
                const float lo = __uint_as_float(uu << 16);
                const float hi = __uint_as_float(uu & 0xffff0000u);
                af.u[p] = pk_bf16(lo * c, hi * c);
            }
        }
        union { uint4 q; short8_t v; } b0, b1;
        b0.q = wf[(size_t)kk * 128];
        b1.q = wf[(size_t)kk * 128 + 64];

        acc0 = __builtin_amdgcn_mfma_f32_16x16x32_bf16(af.v, b0.v, acc0, 0, 0, 0);
        acc1 = __builtin_amdgcn_mfma_f32_16x16x32_bf16(af.v, b1.v, acc1, 0, 0, 0);
    }

#pragma unroll
    for (int r = 0; r < 4; ++r) {
        const int row = m * 16 + (l >> 4) * 4 + r;
        red[ks][row][(l & 15)]      = acc0[r];
        red[ks][row][16 + (l & 15)] = acc1[r];
    }
    __syncthreads();
#pragma unroll
    for (int q = 0; q < 4; ++q) {
        const int j = q * 512 + t;                  // j = b*32 + d
        const int b = j >> 5, d = j & 31;
        spart[((size_t)n * SCH_ + ch) * (B_ * D_) + j] = red[0][b][d] + red[1][b][d];
    }
}

// ---------------- reduce + squash; emit ofrag (update B-frags) or out ----------
template<int FINAL>
__global__ __launch_bounds__(256) void k_reduce(const float* __restrict__ spart,
                                                unsigned int* __restrict__ ofrag_u32,
                                                float* __restrict__ out,
                                                float prescale) {
    const int gt = blockIdx.x * 256 + threadIdx.x;   // N*B*D threads
    const int n = gt >> 11;
    const int rem = gt & 2047;                        // b*32 + d
    const int b = rem >> 5, d = rem & 31;
    const float* sp = spart + (size_t)n * (SCH_ * B_ * D_) + rem;
    float s = 0.f;
#pragma unroll
    for (int p = 0; p < SCH_; ++p) s += sp[p * (B_ * D_)];
    s *= prescale;

    float sq = s * s;
#pragma unroll
    for (int off = 16; off >= 1; off >>= 1) sq += __shfl_xor(sq, off, 64);
    const float scale = sq / ((1.0f + sq) * sqrtf(sq + 1e-7f));
    const float o = scale * s;
    if (FINAL) {
        out[((size_t)b * N_ + n) * D_ + d] = o;       // [B][N][D]
    } else {
        const float o_next = __shfl_down(o, 1, 64);
        if ((d & 1) == 0) {
            const unsigned int val = pk_bf16(o, o_next);
            const int l = (d >> 3) * 16 + (b & 15);
            ofrag_u32[(((n * 4 + (b >> 4)) * 64) + l) * 4 + ((d & 7) >> 1)] = val;
        }
    }
}

// ---------------- fused b-update + softmax (verified r12) ----------------
template<int FIRST>
__global__ __launch_bounds__(512, 2) void k_updsm(const uint4* __restrict__ wfu,
                                                  const float* __restrict__ inT,
                                                  const uint4* __restrict__ ofrag,
                                                  float* __restrict__ bT,
                                                  float* __restrict__ cT) {
    const int t = threadIdx.x, w = t >> 6, l = t & 63;
    const int btile = w & 3;
    const int i = blockIdx.x * 2 + (w >> 2);
    const int g = l >> 4, kl = l & 15;
    const int bp = btile * 16 + kl;           // b'

    float x4[4];
    {
        const float* xp = inT + (size_t)i * (K_ * B_) + bp;
#pragma unroll
        for (int r = 0; r < 4; ++r) x4[r] = xp[(4 * g + r) * B_];
    }

    float bn[N_];
#pragma unroll
    for (int n = 0; n < N_; ++n) {
        union { uint4 q; short8_t v; } of, af;
        of.q = ofrag[(n * 4 + btile) * 64 + l];
        af.q = wfu[((size_t)n * I_ + i) * 64 + l];
        f32x4_t acc = {0.f, 0.f, 0.f, 0.f};
        acc = __builtin_amdgcn_mfma_f32_16x16x32_bf16(af.v, of.v, acc, 0, 0, 0);
        float gp = 0.f;
#pragma unroll
        for (int r = 0; r < 4; ++r) gp = fmaf(acc[r], x4[r], gp);
        gp += __shfl_xor(gp, 16, 64);
        gp += __shfl_xor(gp, 32, 64);
        const size_t bi = ((size_t)n * I_ + i) * B_ + bp;
        if (FIRST) {
            if (l < 16) bT[bi] = gp;
        } else {
            gp += bT[bi];
        }
        bn[n] = gp;
    }

    float mx = bn[0];
#pragma unroll
    for (int n = 1; n < N_; ++n) mx = fmaxf(mx, bn[n]);
    float sum = 0.f;
#pragma unroll
    for (int n = 0; n < N_; ++n) { bn[n] = __expf(bn[n] - mx); sum += bn[n]; }
    const float inv = 1.0f / sum;
    if (l < 16) {
#pragma unroll
        for (int n = 0; n < N_; ++n)
            cT[((size_t)n * I_ + i) * B_ + bp] = bn[n] * inv;
    }
}

extern "C" void kernel_launch(void* const* d_in, const int* in_sizes, int n_in,
                              void* d_out, int out_size, void* d_ws, size_t ws_size,
                              hipStream_t stream) {
    const float* inputs = (const float*)d_in[0];
    const float* W      = (const float*)d_in[1];
    float* out = (float*)d_out;
    float* ws  = (float*)d_ws;
    float* inT   = ws + OFF_INT;
    float* cT    = ws + OFF_CT;
    float* bT    = ws + OFF_BT;
    float* spart = ws + OFF_SPART;
    unsigned int* ofrag_u32 = (unsigned int*)(ws + OFF_OFRAG);
    uint4* ofrag = (uint4*)(ws + OFF_OFRAG);
    uint4* xfrag = (uint4*)(ws + OFF_XFRAG);
    uint4* wfs   = (uint4*)(ws + OFF_WFS);
    uint4* wfu   = (uint4*)(ws + OFF_WFU);

    k_wpack<<<dim3(I_ / 16, N_), 512, 0, stream>>>(W, wfs, wfu);
    k_prep<<<I_, 256, 0, stream>>>(inputs, inT, xfrag);
    // r = 0 (uniform c = 1/N as prescale)
    k_sweep_mfma<1><<<dim3(SCH_, N_), 512, 0, stream>>>(wfs, xfrag, cT, spart);
    k_reduce<0><<<256, 256, 0, stream>>>(spart, ofrag_u32, out, 1.0f / N_);
    k_updsm<1><<<I_ / 2, 512, 0, stream>>>(wfu, inT, ofrag, bT, cT);
    // r = 1
    k_sweep_mfma<0><<<dim3(SCH_, N_), 512, 0, stream>>>(wfs, xfrag, cT, spart);
    k_reduce<0><<<256, 256, 0, stream>>>(spart, ofrag_u32, out, 1.0f);
    k_updsm<0><<<I_ / 2, 512, 0, stream>>>(wfu, inT, ofrag, bT, cT);
    // r = 2
    k_sweep_mfma<0><<<dim3(SCH_, N_), 512, 0, stream>>>(wfs, xfrag, cT, spart);
    k_reduce<1><<<256, 256, 0, stream>>>(spart, ofrag_u32, out, 1.0f);
}

// Round 14
// 176.725 us; speedup vs baseline: 1.0215x; 1.0215x over previous
//
#include <hip/hip_runtime.h>
#include <hip/hip_bf16.h>
#include <math.h>

#define B_ 64
#define I_ 2048
#define K_ 16
#define N_ 32
#define D_ 32
#define SCH_ 16     // i-chunks for mfma sweep (128 i each)

#define AS1 __attribute__((address_space(1)))
#define AS3 __attribute__((address_space(3)))

typedef __attribute__((ext_vector_type(8))) short short8_t;   // 8 bf16
typedef __attribute__((ext_vector_type(4))) float f32x4_t;

// ws offsets (floats)
#define OFF_INT   0u           // inT   [I][K][B]        2097152
#define OFF_CT    2097152u     // cT    [N][I][B]        4194304
#define OFF_BT    6291456u     // bT    [N][I][B]        4194304
#define OFF_SPART 10485760u    // spart [N][SCH][B][D]   1048576
#define OFF_OFRAG 11534336u    // ofrag [N][4][64] uint4 =  32768 f-slots
#define OFF_XFRAG 11599872u    // xfrag [4][1024][64] uint4 = 1048576 f-slots
#define OFF_WFS   12648448u    // wfs [N][1024][2][64] uint4 = 16777216 (64 MiB)
#define OFF_WFU   29425664u    // wfu [N][I][64] uint4       = 16777216 (64 MiB)
// total 176.25 MiB (ws = 512 MiB per harness poison fills)

__device__ __forceinline__ unsigned int pk_bf16(float lo, float hi) {
    union { __hip_bfloat162 h2; unsigned int u; } cv;
    cv.h2 = __float22bfloat162_rn(float2{lo, hi});
    return cv.u;
}

// swizzled LDS accessors: LDS granule slot S holds global granule S^((S>>5)&7)
// (involution: reading global granule G -> slot G^((G>>5)&7))
__device__ __forceinline__ float lds_rd(const float* lds, int A) {   // A: float offset
    const int G = A >> 2;
    const int S = G ^ ((G >> 5) & 7);
    return lds[(S << 2) | (A & 3)];
}
__device__ __forceinline__ float4 lds_rd4(const float* lds, int A) { // A: 4-float aligned
    const int G = A >> 2;
    const int S = G ^ ((G >> 5) & 7);
    return *(const float4*)(lds + (S << 2));
}

// ---------------- fused: transpose inputs -> inT  +  pack xfrag ----------------
__global__ __launch_bounds__(256) void k_prep(const float* __restrict__ in,
                                              float* __restrict__ inT,
                                              uint4* __restrict__ xfrag) {
    __shared__ float lds[B_][K_ + 1];
    const int i = blockIdx.x;
    const int t = threadIdx.x;
    const int b = t >> 2, kq = t & 3;
    const float4 v = *(const float4*)(in + ((size_t)b * I_ + i) * K_ + kq * 4);
    lds[b][kq * 4 + 0] = v.x; lds[b][kq * 4 + 1] = v.y;
    lds[b][kq * 4 + 2] = v.z; lds[b][kq * 4 + 3] = v.w;
    __syncthreads();
#pragma unroll
    for (int q = 0; q < 4; ++q) {
        const int j = t + q * 256;          // j = k*64 + b
        const int k = j >> 6, bb = j & 63;
        inT[(size_t)i * (K_ * B_) + j] = lds[bb][k];
    }
    if (t < 128) {
        const int m = t >> 5, r = t & 31, gl = r >> 4, kl = r & 15;
        const int bb = m * 16 + kl, k0 = 8 * gl;
        union { unsigned int u[4]; uint4 q; } o;
#pragma unroll
        for (int p = 0; p < 4; ++p)
            o.u[p] = pk_bf16(lds[bb][k0 + 2 * p], lds[bb][k0 + 2 * p + 1]);
        xfrag[((size_t)m * 1024 + (i >> 1)) * 64 + (2 * (i & 1) + gl) * 16 + kl] = o.q;
    }
}

// ---------------- pre-pack W -> bf16 fragments (single-barrier + swizzle) --------
// 512 thr, 16 i per block. Stage ALL 64 KB -> 32 KB LDS (4 loads/thread in
// flight, granule-swizzled), ONE barrier, then emit: waves 0-3 wfu, 4-7 wfs.
__global__ __launch_bounds__(512, 4) void k_wpack(const float* __restrict__ W,
                                                  uint4* __restrict__ wfs,
                                                  uint4* __restrict__ wfu) {
    __shared__ __align__(16) float lds[8192];    // 32 KB = 16 i
    const int ib = blockIdx.x * 16;
    const int n = blockIdx.y;
    const int t = threadIdx.x, w = t >> 6;
    const float4* wg4 = (const float4*)(W + ((size_t)n * I_ + ib) * 512);

#pragma unroll
    for (int sc = 0; sc < 4; ++sc) {
        const int S = sc * 512 + t;                 // LDS granule slot
        const int gg = S ^ ((S >> 5) & 7);          // global granule (swizzle src)
        __builtin_amdgcn_global_load_lds(
            (const AS1 void*)(const void*)(wg4 + gg),
            (AS3 void*)(void*)((float4*)lds + sc * 512 + w * 64), 16, 0, 0);
    }
    __syncthreads();

    if (t < 256) {
        // wfu A-frags: 4 per thread (one per sc); il = wave id
        const int il = t >> 6, l = t & 63, g = l >> 4, kl = l & 15;
#pragma unroll
        for (int sc = 0; sc < 4; ++sc) {
            const int base = (sc * 4 + il) * 512;
            union { unsigned int u[4]; uint4 q; } o;
#pragma unroll
            for (int p = 0; p < 4; ++p)
                o.u[p] = pk_bf16(lds_rd(lds, base + (8 * g + 2 * p) * 16 + kl),
                                 lds_rd(lds, base + (8 * g + 2 * p + 1) * 16 + kl));
            wfu[((size_t)n * I_ + ib + sc * 4 + il) * 64 + l] = o.q;
        }
    } else {
        // wfs B-frags: 4 per thread (one per sc)
        const int u2 = t - 256;
        const int kkl = u2 >> 7, r = u2 & 127, nt = r >> 6, l = r & 63, g = l >> 4;
        const int Floc = kkl * 1024 + (g >> 1) * 512 + nt * 256
                         + (l & 15) * 16 + (g & 1) * 8;
#pragma unroll
        for (int sc = 0; sc < 4; ++sc) {
            const int F = sc * 2048 + Floc;
            const float4 f0 = lds_rd4(lds, F);
            const float4 f1 = lds_rd4(lds, F + 4);
            union { unsigned int u[4]; uint4 q; } o;
            o.u[0] = pk_bf16(f0.x, f0.y); o.u[1] = pk_bf16(f0.z, f0.w);
            o.u[2] = pk_bf16(f1.x, f1.y); o.u[3] = pk_bf16(f1.z, f1.w);
            const int kk = (ib >> 1) + sc * 2 + kkl;
            wfs[(((size_t)n * 1024 + kk) * 2 + nt) * 64 + l] = o.q;
        }
    }
}

// ---------------- MFMA s-sweep (verified r11) ----------------
template<int UNIFORM>
__global__ __launch_bounds__(512, 2) void k_sweep_mfma(const uint4* __restrict__ wfs,
                                                       const uint4* __restrict__ xfrag,
                                                       const float* __restrict__ cT,
                                                       float* __restrict__ spart) {
    __shared__ float red[2][B_][D_ + 1];
    const int n = blockIdx.y, ch = blockIdx.x;
    const int t = threadIdx.x, w = t >> 6, l = t & 63;
    const int m = w >> 1, ks = w & 1;

    f32x4_t acc0 = {0.f, 0.f, 0.f, 0.f};
    f32x4_t acc1 = {0.f, 0.f, 0.f, 0.f};

    const uint4* xf = xfrag + (size_t)m * 65536 + l;            // + kk*64
    const uint4* wf = wfs + (size_t)n * (1024 * 128) + l;       // + kk*128 (+64 nt=1)
    const int kk0 = ch * 64 + ks * 32;

    for (int tt = 0; tt < 32; ++tt) {
        const int kk = kk0 + tt;
        union { uint4 q; unsigned int u[4]; } xv;
        xv.q = xf[(size_t)kk * 64];
        union { unsigned int u[4]; short8_t v; } af;
        if (UNIFORM) {
            af.u[0] = xv.u[0]; af.u[1] = xv.u[1];
            af.u[2] = xv.u[2]; af.u[3] = xv.u[3];
        } else {
            const float c = cT[((size_t)n * I_ + 2 * kk + (l >> 5)) * B_
                               + m * 16 + (l & 15)];
#pragma unroll
            for (int p = 0; p < 4; ++p) {
                const unsigned int uu = xv.u[p];
                const float lo = __uint_as_float(uu << 16);
                const float hi = __uint_as_float(uu & 0xffff0000u);
                af.u[p] = pk_bf16(lo * c, hi * c);
            }
        }
        union { uint4 q; short8_t v; } b0, b1;
        b0.q = wf[(size_t)kk * 128];
        b1.q = wf[(size_t)kk * 128 + 64];

        acc0 = __builtin_amdgcn_mfma_f32_16x16x32_bf16(af.v, b0.v, acc0, 0, 0, 0);
        acc1 = __builtin_amdgcn_mfma_f32_16x16x32_bf16(af.v, b1.v, acc1, 0, 0, 0);
    }

#pragma unroll
    for (int r = 0; r < 4; ++r) {
        const int row = m * 16 + (l >> 4) * 4 + r;
        red[ks][row][(l & 15)]      = acc0[r];
        red[ks][row][16 + (l & 15)] = acc1[r];
    }
    __syncthreads();
#pragma unroll
    for (int q = 0; q < 4; ++q) {
        const int j = q * 512 + t;                  // j = b*32 + d
        const int b = j >> 5, d = j & 31;
        spart[((size_t)n * SCH_ + ch) * (B_ * D_) + j] = red[0][b][d] + red[1][b][d];
    }
}

// ---------------- reduce + squash; emit ofrag (update B-frags) or out ----------
template<int FINAL>
__global__ __launch_bounds__(256) void k_reduce(const float* __restrict__ spart,
                                                unsigned int* __restrict__ ofrag_u32,
                                                float* __restrict__ out,
                                                float prescale) {
    const int gt = blockIdx.x * 256 + threadIdx.x;   // N*B*D threads
    const int n = gt >> 11;
    const int rem = gt & 2047;                        // b*32 + d
    const int b = rem >> 5, d = rem & 31;
    const float* sp = spart + (size_t)n * (SCH_ * B_ * D_) + rem;
    float s = 0.f;
#pragma unroll
    for (int p = 0; p < SCH_; ++p) s += sp[p * (B_ * D_)];
    s *= prescale;

    float sq = s * s;
#pragma unroll
    for (int off = 16; off >= 1; off >>= 1) sq += __shfl_xor(sq, off, 64);
    const float scale = sq / ((1.0f + sq) * sqrtf(sq + 1e-7f));
    const float o = scale * s;
    if (FINAL) {
        out[((size_t)b * N_ + n) * D_ + d] = o;       // [B][N][D]
    } else {
        const float o_next = __shfl_down(o, 1, 64);
        if ((d & 1) == 0) {
            const unsigned int val = pk_bf16(o, o_next);
            const int l = (d >> 3) * 16 + (b & 15);
            ofrag_u32[(((n * 4 + (b >> 4)) * 64) + l) * 4 + ((d & 7) >> 1)] = val;
        }
    }
}

// ---------------- fused b-update + softmax (verified r12) ----------------
template<int FIRST>
__global__ __launch_bounds__(512, 2) void k_updsm(const uint4* __restrict__ wfu,
                                                  const float* __restrict__ inT,
                                                  const uint4* __restrict__ ofrag,
                                                  float* __restrict__ bT,
                                                  float* __restrict__ cT) {
    const int t = threadIdx.x, w = t >> 6, l = t & 63;
    const int btile = w & 3;
    const int i = blockIdx.x * 2 + (w >> 2);
    const int g = l >> 4, kl = l & 15;
    const int bp = btile * 16 + kl;           // b'

    float x4[4];
    {
        const float* xp = inT + (size_t)i * (K_ * B_) + bp;
#pragma unroll
        for (int r = 0; r < 4; ++r) x4[r] = xp[(4 * g + r) * B_];
    }

    float bn[N_];
#pragma unroll
    for (int n = 0; n < N_; ++n) {
        union { uint4 q; short8_t v; } of, af;
        of.q = ofrag[(n * 4 + btile) * 64 + l];
        af.q = wfu[((size_t)n * I_ + i) * 64 + l];
        f32x4_t acc = {0.f, 0.f, 0.f, 0.f};
        acc = __builtin_amdgcn_mfma_f32_16x16x32_bf16(af.v, of.v, acc, 0, 0, 0);
        float gp = 0.f;
#pragma unroll
        for (int r = 0; r < 4; ++r) gp = fmaf(acc[r], x4[r], gp);
        gp += __shfl_xor(gp, 16, 64);
        gp += __shfl_xor(gp, 32, 64);
        const size_t bi = ((size_t)n * I_ + i) * B_ + bp;
        if (FIRST) {
            if (l < 16) bT[bi] = gp;
        } else {
            gp += bT[bi];
        }
        bn[n] = gp;
    }

    float mx = bn[0];
#pragma unroll
    for (int n = 1; n < N_; ++n) mx = fmaxf(mx, bn[n]);
    float sum = 0.f;
#pragma unroll
    for (int n = 0; n < N_; ++n) { bn[n] = __expf(bn[n] - mx); sum += bn[n]; }
    const float inv = 1.0f / sum;
    if (l < 16) {
#pragma unroll
        for (int n = 0; n < N_; ++n)
            cT[((size_t)n * I_ + i) * B_ + bp] = bn[n] * inv;
    }
}

extern "C" void kernel_launch(void* const* d_in, const int* in_sizes, int n_in,
                              void* d_out, int out_size, void* d_ws, size_t ws_size,
                              hipStream_t stream) {
    const float* inputs = (const float*)d_in[0];
    const float* W      = (const float*)d_in[1];
    float* out = (float*)d_out;
    float* ws  = (float*)d_ws;
    float* inT   = ws + OFF_INT;
    float* cT    = ws + OFF_CT;
    float* bT    = ws + OFF_BT;
    float* spart = ws + OFF_SPART;
    unsigned int* ofrag_u32 = (unsigned int*)(ws + OFF_OFRAG);
    uint4* ofrag = (uint4*)(ws + OFF_OFRAG);
    uint4* xfrag = (uint4*)(ws + OFF_XFRAG);
    uint4* wfs   = (uint4*)(ws + OFF_WFS);
    uint4* wfu   = (uint4*)(ws + OFF_WFU);

    k_wpack<<<dim3(I_ / 16, N_), 512, 0, stream>>>(W, wfs, wfu);
    k_prep<<<I_, 256, 0, stream>>>(inputs, inT, xfrag);
    // r = 0 (uniform c = 1/N as prescale)
    k_sweep_mfma<1><<<dim3(SCH_, N_), 512, 0, stream>>>(wfs, xfrag, cT, spart);
    k_reduce<0><<<256, 256, 0, stream>>>(spart, ofrag_u32, out, 1.0f / N_);
    k_updsm<1><<<I_ / 2, 512, 0, stream>>>(wfu, inT, ofrag, bT, cT);
    // r = 1
    k_sweep_mfma<0><<<dim3(SCH_, N_), 512, 0, stream>>>(wfs, xfrag, cT, spart);
    k_reduce<0><<<256, 256, 0, stream>>>(spart, ofrag_u32, out, 1.0f);
    k_updsm<0><<<I_ / 2, 512, 0, stream>>>(wfu, inT, ofrag, bT, cT);
    // r = 2
    k_sweep_mfma<0><<<dim3(SCH_, N_), 512, 0, stream>>>(wfs, xfrag, cT, spart);
    k_reduce<1><<<256, 256, 0, stream>>>(spart, ofrag_u32, out, 1.0f);
}